// Round 7
// baseline (61.745 us; speedup 1.0000x reference)
//
#include <hip/hip_runtime.h>
#include <hip/hip_cooperative_groups.h>

namespace cg = cooperative_groups;

#define BATCH 32
#define SEQ 2048
#define NTOT (BATCH * SEQ)
#define EPS 1e-8f
#define BLK 256
#define SEGS 16
#define SEGLEN (SEQ / SEGS)       // 128 floats per segment
#define LDSW (SEGLEN + 4)         // +4-word pad -> 2-way bank aliasing only (free)
#define E 8                       // pred elements per thread (register-blocked)
#define GRP (BLK / SEGS)          // 16 pred groups per block
#define CBLK (GRP * E)            // 128 pred elements per block
#define NCH (SEQ / CBLK)          // 16 chunks per batch row
#define NPART (BATCH * NCH)       // 512 per-block partials
#define PADV 1e30f

// ---- ws layout (4-byte words) ---- plain overwrites only, no atomics/zeroing
#define WS_SJ    0
#define WS_SSDM  (NPART)
#define WS_SSDI  (2 * NPART)
#define WS_SGNM  (3 * NPART)
#define WS_SGNI  (4 * NPART)
#define WS_AMZ   (5 * NPART)
#define WS_AIN   (6 * NPART)
#define WS_PLEN  (7 * NPART)       // int [32]
#define WS_MLEN  (7 * NPART + 32)  // int [32]

__device__ inline float waveSum(float v) {
    #pragma unroll
    for (int off = 32; off; off >>= 1) v += __shfl_xor(v, off);
    return v;
}
__device__ inline float waveMax(float v) {
    #pragma unroll
    for (int off = 32; off; off >>= 1) v = fmaxf(v, __shfl_xor(v, off));
    return v;
}
__device__ inline int waveMaxI(int v) {
    #pragma unroll
    for (int off = 32; off; off >>= 1) v = max(v, __shfl_xor(v, off));
    return v;
}
__device__ inline float fsign(float x) {
    return (x > 0.0f) ? 1.0f : ((x < 0.0f) ? -1.0f : 0.0f);
}

// ==== single cooperative kernel: grid (BATCH, NCH) x BLK ====
// Phase 1: per-block partial losses (R4 structure, E=8 register-blocked scan).
// grid.sync(). Phase 2: block (0,0) reduces 512 partials -> 4 outputs.
__global__ __launch_bounds__(BLK)
void k_fused(const float* __restrict__ pmz,  const float* __restrict__ mz,
             const float* __restrict__ inten, const float* __restrict__ pint,
             float* __restrict__ wf, int* __restrict__ wi,
             float* __restrict__ out) {
    const int b = blockIdx.x;
    const int c = blockIdx.y;
    const int t = threadIdx.x;
    const int wid = t >> 6;

    __shared__ float mzs[SEGS * LDSW];
    __shared__ int   smP[4], smM[4];
    __shared__ float red[7][4];

    const float* mzrow = mz  + (size_t)b * SEQ;
    const float* prow  = pmz + (size_t)b * SEQ;

    // ---- stage mz row to LDS (segment-padded) + last-negative scans ----
    const int base  = t * 8;                        // word index in row
    const int lbase = base + ((base >> 7) << 2);    // +4 words per 128-word seg
    float4 mv0 = *(const float4*)(mzrow + base);
    float4 mv1 = *(const float4*)(mzrow + base + 4);
    float4 pv0 = *(const float4*)(prow  + base);
    float4 pv1 = *(const float4*)(prow  + base + 4);
    *(float4*)(mzs + lbase)     = mv0;
    *(float4*)(mzs + lbase + 4) = mv1;

    int lm = 0, lp = 0;   // ascending overwrite == index of last negative
    if (mv0.x < 0.f) lm = base + 0;  if (mv0.y < 0.f) lm = base + 1;
    if (mv0.z < 0.f) lm = base + 2;  if (mv0.w < 0.f) lm = base + 3;
    if (mv1.x < 0.f) lm = base + 4;  if (mv1.y < 0.f) lm = base + 5;
    if (mv1.z < 0.f) lm = base + 6;  if (mv1.w < 0.f) lm = base + 7;
    if (pv0.x < 0.f) lp = base + 0;  if (pv0.y < 0.f) lp = base + 1;
    if (pv0.z < 0.f) lp = base + 2;  if (pv0.w < 0.f) lp = base + 3;
    if (pv1.x < 0.f) lp = base + 4;  if (pv1.y < 0.f) lp = base + 5;
    if (pv1.z < 0.f) lp = base + 6;  if (pv1.w < 0.f) lp = base + 7;
    lm = waveMaxI(lm);  lp = waveMaxI(lp);
    if ((t & 63) == 0) { smM[wid] = lm; smP[wid] = lp; }
    __syncthreads();
    const int mlen = max(max(smM[0], smM[1]), max(smM[2], smM[3]));
    const int plen = max(max(smP[0], smP[1]), max(smP[2], smP[3]));

    // pad invalid tail: min -> ~1e30 -> exp -> 0 (also handles mlen==0)
    #pragma unroll
    for (int k = 0; k < 8; ++k)
        if (base + k >= mlen) mzs[lbase + k] = PADV;
    __syncthreads();

    // ---- stats on threads t < CBLK (one element each) ----
    float ssd_m = 0.f, ssd_i = 0.f, sgn_m = 0.f, sgn_i = 0.f, amz = 0.f, ain = 0.f;
    if (t < CBLK) {
        const int i = c * CBLK + t;
        const size_t idx = (size_t)b * SEQ + i;
        const float a  = prow[i];
        const float bm = mzrow[i];
        const float ci = pint[idx];
        const float di = inten[idx];
        float dm = a - bm;   ssd_m = dm * dm;
        float dd = ci - di;  ssd_i = dd * dd;
        sgn_m = fabsf(fsign(a)  - fsign(bm));
        sgn_i = fabsf(fsign(ci) - fsign(di));
        amz = fabsf(bm);
        ain = fabsf(di);
    }

    // ---- register-blocked min-scan ----
    const int s  = t & (SEGS - 1);       // segment id
    const int ig = t >> 4;               // pred group
    const int pb = c * CBLK + ig * E;    // first pred element of this thread
    float4 pa0 = *(const float4*)(prow + pb);
    float4 pa1 = *(const float4*)(prow + pb + 4);
    float a[E] = {pa0.x, pa0.y, pa0.z, pa0.w, pa1.x, pa1.y, pa1.z, pa1.w};
    float mn[E];
    #pragma unroll
    for (int e = 0; e < E; ++e) mn[e] = PADV;

    const float4* seg4 = (const float4*)(mzs + s * LDSW);
    #pragma unroll 4
    for (int j = 0; j < SEGLEN / 4; ++j) {
        float4 v = seg4[j];
        #pragma unroll
        for (int e = 0; e < E; ++e) {
            float d0 = a[e] - v.x, d1 = a[e] - v.y;
            float d2 = a[e] - v.z, d3 = a[e] - v.w;
            mn[e] = fminf(mn[e], fminf(fabsf(d0), fabsf(d1)));  // -> v_min3 |.|
            mn[e] = fminf(mn[e], fminf(fabsf(d2), fabsf(d3)));
        }
    }
    // combine the 16 segment minima (lanes ig*16 .. ig*16+15)
    #pragma unroll
    for (int e = 0; e < E; ++e) {
        float m = mn[e];
        m = fminf(m, __shfl_xor(m, 1));
        m = fminf(m, __shfl_xor(m, 2));
        m = fminf(m, __shfl_xor(m, 4));
        m = fminf(m, __shfl_xor(m, 8));
        mn[e] = m;
    }

    // contribution: s==0 lane of each group handles its 8 preds
    float contrib = 0.0f;
    if (s == 0) {
        const float* pintrow = pint + (size_t)b * SEQ;
        float4 w0 = *(const float4*)(pintrow + pb);
        float4 w1 = *(const float4*)(pintrow + pb + 4);
        float w[E] = {w0.x, w0.y, w0.z, w0.w, w1.x, w1.y, w1.z, w1.w};
        #pragma unroll
        for (int e = 0; e < E; ++e)
            if (pb + e < plen) contrib += __expf(-2.0f * mn[e]) * w[e];
    }

    // ---- block-reduce 7 partials ----
    float s0 = waveSum(contrib);
    float s1 = waveSum(ssd_m);
    float s2 = waveSum(ssd_i);
    float s3 = waveSum(sgn_m);
    float s4 = waveSum(sgn_i);
    float s5 = waveMax(amz);
    float s6 = waveMax(ain);
    if ((t & 63) == 0) {
        red[0][wid] = s0; red[1][wid] = s1; red[2][wid] = s2; red[3][wid] = s3;
        red[4][wid] = s4; red[5][wid] = s5; red[6][wid] = s6;
    }
    __syncthreads();
    if (t == 0) {
        const int bc = b * NCH + c;
        wf[WS_SJ   + bc] = red[0][0] + red[0][1] + red[0][2] + red[0][3];
        wf[WS_SSDM + bc] = red[1][0] + red[1][1] + red[1][2] + red[1][3];
        wf[WS_SSDI + bc] = red[2][0] + red[2][1] + red[2][2] + red[2][3];
        wf[WS_SGNM + bc] = red[3][0] + red[3][1] + red[3][2] + red[3][3];
        wf[WS_SGNI + bc] = red[4][0] + red[4][1] + red[4][2] + red[4][3];
        wf[WS_AMZ  + bc] = fmaxf(fmaxf(red[5][0], red[5][1]), fmaxf(red[5][2], red[5][3]));
        wf[WS_AIN  + bc] = fmaxf(fmaxf(red[6][0], red[6][1]), fmaxf(red[6][2], red[6][3]));
        if (c == 0) { wi[WS_PLEN + b] = plen; wi[WS_MLEN + b] = mlen; }
        __threadfence();   // publish partials device-wide before grid barrier
    }

    // ================= grid-wide barrier =================
    cg::this_grid().sync();

    // ================= phase 2: block (0,0) finalizes =================
    if (b != 0 || c != 0) return;

    __shared__ float terms[BATCH];
    __shared__ float red2[6][4];

    // soft-jaccard: batch bb's 16 partials at [16bb,16bb+16); thread t holds 2t,2t+1
    float2 v = *(const float2*)(wf + WS_SJ + 2 * t);
    float sj = v.x + v.y;
    sj += __shfl_xor(sj, 1);
    sj += __shfl_xor(sj, 2);
    sj += __shfl_xor(sj, 4);
    if ((t & 7) == 0) {
        int bb = t >> 3;
        float su = (float)(wi[WS_PLEN + bb] + wi[WS_MLEN + bb]);
        terms[bb] = 1.0f - (sj + EPS) / (su + EPS);
    }

    // stats partial combine (float2 per thread, then block reduce)
    float2 q1 = *(const float2*)(wf + WS_SSDM + 2 * t);
    float2 q2 = *(const float2*)(wf + WS_SSDI + 2 * t);
    float2 q3 = *(const float2*)(wf + WS_SGNM + 2 * t);
    float2 q4 = *(const float2*)(wf + WS_SGNI + 2 * t);
    float2 q5 = *(const float2*)(wf + WS_AMZ  + 2 * t);
    float2 q6 = *(const float2*)(wf + WS_AIN  + 2 * t);
    float v1 = q1.x + q1.y;
    float v2 = q2.x + q2.y;
    float v3 = q3.x + q3.y;
    float v4 = q4.x + q4.y;
    float v5 = fmaxf(q5.x, q5.y);
    float v6 = fmaxf(q6.x, q6.y);
    v1 = waveSum(v1); v2 = waveSum(v2); v3 = waveSum(v3); v4 = waveSum(v4);
    v5 = waveMax(v5); v6 = waveMax(v6);
    if ((t & 63) == 0) {
        red2[0][wid] = v1; red2[1][wid] = v2; red2[2][wid] = v3;
        red2[3][wid] = v4; red2[4][wid] = v5; red2[5][wid] = v6;
    }
    __syncthreads();

    // wave 0: sum the 32 batch terms
    float term = (t < BATCH) ? terms[t] : 0.0f;
    if (t < 64) term = waveSum(term);

    if (t == 0) {
        float fssd_m = red2[0][0] + red2[0][1] + red2[0][2] + red2[0][3];
        float fssd_i = red2[1][0] + red2[1][1] + red2[1][2] + red2[1][3];
        float fsgn_m = red2[2][0] + red2[2][1] + red2[2][2] + red2[2][3];
        float fsgn_i = red2[3][0] + red2[3][1] + red2[3][2] + red2[3][3];
        float famz = fmaxf(fmaxf(red2[4][0], red2[4][1]), fmaxf(red2[4][2], red2[4][3]));
        float fain = fmaxf(fmaxf(red2[5][0], red2[5][1]), fmaxf(red2[5][2], red2[5][3]));
        out[0] = term / (float)BATCH;
        out[1] = (fssd_m / (float)NTOT) / (famz * famz);
        out[2] = (fssd_i / (float)NTOT) / (fain * fain);
        out[3] = 0.1f * 0.5f * (fsgn_m + fsgn_i) / (float)NTOT;
    }
}

extern "C" void kernel_launch(void* const* d_in, const int* in_sizes, int n_in,
                              void* d_out, int out_size, void* d_ws, size_t ws_size,
                              hipStream_t stream) {
    const float* pred_mz = (const float*)d_in[0];
    const float* mz      = (const float*)d_in[1];
    const float* inten   = (const float*)d_in[2];
    const float* pint    = (const float*)d_in[3];
    float* out = (float*)d_out;
    float* wf = (float*)d_ws;
    int*   wi = (int*)d_ws;

    void* args[] = {(void*)&pred_mz, (void*)&mz, (void*)&inten, (void*)&pint,
                    (void*)&wf, (void*)&wi, (void*)&out};
    hipLaunchCooperativeKernel((const void*)k_fused, dim3(BATCH, NCH), dim3(BLK),
                               args, 0, stream);
}

// Round 8
// 27.648 us; speedup vs baseline: 2.2332x; 2.2332x over previous
//
#include <hip/hip_runtime.h>

#define BATCH 32
#define SEQ 2048
#define NTOT (BATCH * SEQ)
#define EPS 1e-8f
#define BLK 256
#define SEGS 16
#define SEGLEN (SEQ / SEGS)       // 128 floats per segment
#define LDSW (SEGLEN + 4)         // +4-word pad -> 2-way bank aliasing only (free)
#define E 8                       // pred elements per thread (register-blocked)
#define GRP (BLK / SEGS)          // 16 pred groups per block
#define CBLK (GRP * E)            // 128 pred elements per block
#define NCH (SEQ / CBLK)          // 16 chunks per batch row
#define NPART (BATCH * NCH)       // 512 per-block partials
#define NBLOCKS (BATCH * NCH)
#define PADV 1e30f

// ---- ws layout (4-byte words) ----
#define WS_SJ    0
#define WS_SSDM  (NPART)
#define WS_SSDI  (2 * NPART)
#define WS_SGNM  (3 * NPART)
#define WS_SGNI  (4 * NPART)
#define WS_AMZ   (5 * NPART)
#define WS_AIN   (6 * NPART)
#define WS_PLEN  (7 * NPART)       // int [32]
#define WS_MLEN  (7 * NPART + 32)  // int [32]
#define WS_CNT   (7 * NPART + 80)  // int [1], own cache line; reset by k_init

#define AST_F(p, v) __hip_atomic_store((p), (v), __ATOMIC_RELAXED, __HIP_MEMORY_SCOPE_AGENT)
#define ALD_F(p)    __hip_atomic_load((p), __ATOMIC_RELAXED, __HIP_MEMORY_SCOPE_AGENT)

__device__ inline float waveSum(float v) {
    #pragma unroll
    for (int off = 32; off; off >>= 1) v += __shfl_xor(v, off);
    return v;
}
__device__ inline float waveMax(float v) {
    #pragma unroll
    for (int off = 32; off; off >>= 1) v = fmaxf(v, __shfl_xor(v, off));
    return v;
}
__device__ inline int waveMaxI(int v) {
    #pragma unroll
    for (int off = 32; off; off >>= 1) v = max(v, __shfl_xor(v, off));
    return v;
}
__device__ inline float fsign(float x) {
    return (x > 0.0f) ? 1.0f : ((x < 0.0f) ? -1.0f : 0.0f);
}

// ---- 1-thread init: reset arrival counter (replaces pathological memset fill) ----
__global__ void k_init(int* cnt) { *cnt = 0; }

// ==== main kernel: grid (BATCH, NCH) x BLK; last-arriving block finalizes ====
__global__ __launch_bounds__(BLK)
void k_fused(const float* __restrict__ pmz,  const float* __restrict__ mz,
             const float* __restrict__ inten, const float* __restrict__ pint,
             float* __restrict__ wf, int* __restrict__ wi,
             int* __restrict__ cnt, float* __restrict__ out) {
    const int b = blockIdx.x;
    const int c = blockIdx.y;
    const int t = threadIdx.x;
    const int wid = t >> 6;

    __shared__ float mzs[SEGS * LDSW];
    __shared__ int   smP[4], smM[4];
    __shared__ float red[7][4];
    __shared__ int   sflag;

    const float* mzrow = mz  + (size_t)b * SEQ;
    const float* prow  = pmz + (size_t)b * SEQ;

    // ---- stage mz row to LDS (segment-padded) + last-negative scans ----
    const int base  = t * 8;                        // word index in row
    const int lbase = base + ((base >> 7) << 2);    // +4 words per 128-word seg
    float4 mv0 = *(const float4*)(mzrow + base);
    float4 mv1 = *(const float4*)(mzrow + base + 4);
    float4 pv0 = *(const float4*)(prow  + base);
    float4 pv1 = *(const float4*)(prow  + base + 4);
    *(float4*)(mzs + lbase)     = mv0;
    *(float4*)(mzs + lbase + 4) = mv1;

    int lm = 0, lp = 0;   // ascending overwrite == index of last negative
    if (mv0.x < 0.f) lm = base + 0;  if (mv0.y < 0.f) lm = base + 1;
    if (mv0.z < 0.f) lm = base + 2;  if (mv0.w < 0.f) lm = base + 3;
    if (mv1.x < 0.f) lm = base + 4;  if (mv1.y < 0.f) lm = base + 5;
    if (mv1.z < 0.f) lm = base + 6;  if (mv1.w < 0.f) lm = base + 7;
    if (pv0.x < 0.f) lp = base + 0;  if (pv0.y < 0.f) lp = base + 1;
    if (pv0.z < 0.f) lp = base + 2;  if (pv0.w < 0.f) lp = base + 3;
    if (pv1.x < 0.f) lp = base + 4;  if (pv1.y < 0.f) lp = base + 5;
    if (pv1.z < 0.f) lp = base + 6;  if (pv1.w < 0.f) lp = base + 7;
    lm = waveMaxI(lm);  lp = waveMaxI(lp);
    if ((t & 63) == 0) { smM[wid] = lm; smP[wid] = lp; }
    __syncthreads();
    const int mlen = max(max(smM[0], smM[1]), max(smM[2], smM[3]));
    const int plen = max(max(smP[0], smP[1]), max(smP[2], smP[3]));

    // pad invalid tail: min -> ~1e30 -> exp -> 0 (also handles mlen==0)
    #pragma unroll
    for (int k = 0; k < 8; ++k)
        if (base + k >= mlen) mzs[lbase + k] = PADV;
    __syncthreads();

    // ---- stats on threads t < CBLK (one element each) ----
    float ssd_m = 0.f, ssd_i = 0.f, sgn_m = 0.f, sgn_i = 0.f, amz = 0.f, ain = 0.f;
    if (t < CBLK) {
        const int i = c * CBLK + t;
        const size_t idx = (size_t)b * SEQ + i;
        const float a  = prow[i];
        const float bm = mzrow[i];
        const float ci = pint[idx];
        const float di = inten[idx];
        float dm = a - bm;   ssd_m = dm * dm;
        float dd = ci - di;  ssd_i = dd * dd;
        sgn_m = fabsf(fsign(a)  - fsign(bm));
        sgn_i = fabsf(fsign(ci) - fsign(di));
        amz = fabsf(bm);
        ain = fabsf(di);
    }

    // ---- register-blocked min-scan ----
    const int s  = t & (SEGS - 1);       // segment id
    const int ig = t >> 4;               // pred group
    const int pb = c * CBLK + ig * E;    // first pred element of this thread
    float4 pa0 = *(const float4*)(prow + pb);
    float4 pa1 = *(const float4*)(prow + pb + 4);
    float a[E] = {pa0.x, pa0.y, pa0.z, pa0.w, pa1.x, pa1.y, pa1.z, pa1.w};
    float mn[E];
    #pragma unroll
    for (int e = 0; e < E; ++e) mn[e] = PADV;

    const float4* seg4 = (const float4*)(mzs + s * LDSW);
    #pragma unroll 4
    for (int j = 0; j < SEGLEN / 4; ++j) {
        float4 v = seg4[j];
        #pragma unroll
        for (int e = 0; e < E; ++e) {
            float d0 = a[e] - v.x, d1 = a[e] - v.y;
            float d2 = a[e] - v.z, d3 = a[e] - v.w;
            mn[e] = fminf(mn[e], fminf(fabsf(d0), fabsf(d1)));  // -> v_min3 |.|
            mn[e] = fminf(mn[e], fminf(fabsf(d2), fabsf(d3)));
        }
    }
    // combine the 16 segment minima (lanes ig*16 .. ig*16+15)
    #pragma unroll
    for (int e = 0; e < E; ++e) {
        float m = mn[e];
        m = fminf(m, __shfl_xor(m, 1));
        m = fminf(m, __shfl_xor(m, 2));
        m = fminf(m, __shfl_xor(m, 4));
        m = fminf(m, __shfl_xor(m, 8));
        mn[e] = m;
    }

    // contribution: s==0 lane of each group handles its 8 preds
    float contrib = 0.0f;
    if (s == 0) {
        const float* pintrow = pint + (size_t)b * SEQ;
        float4 w0 = *(const float4*)(pintrow + pb);
        float4 w1 = *(const float4*)(pintrow + pb + 4);
        float w[E] = {w0.x, w0.y, w0.z, w0.w, w1.x, w1.y, w1.z, w1.w};
        #pragma unroll
        for (int e = 0; e < E; ++e)
            if (pb + e < plen) contrib += __expf(-2.0f * mn[e]) * w[e];
    }

    // ---- block-reduce 7 partials ----
    float s0 = waveSum(contrib);
    float s1 = waveSum(ssd_m);
    float s2 = waveSum(ssd_i);
    float s3 = waveSum(sgn_m);
    float s4 = waveSum(sgn_i);
    float s5 = waveMax(amz);
    float s6 = waveMax(ain);
    if ((t & 63) == 0) {
        red[0][wid] = s0; red[1][wid] = s1; red[2][wid] = s2; red[3][wid] = s3;
        red[4][wid] = s4; red[5][wid] = s5; red[6][wid] = s6;
    }
    __syncthreads();
    if (t == 0) {
        const int bc = b * NCH + c;
        AST_F(&wf[WS_SJ   + bc], red[0][0] + red[0][1] + red[0][2] + red[0][3]);
        AST_F(&wf[WS_SSDM + bc], red[1][0] + red[1][1] + red[1][2] + red[1][3]);
        AST_F(&wf[WS_SSDI + bc], red[2][0] + red[2][1] + red[2][2] + red[2][3]);
        AST_F(&wf[WS_SGNM + bc], red[3][0] + red[3][1] + red[3][2] + red[3][3]);
        AST_F(&wf[WS_SGNI + bc], red[4][0] + red[4][1] + red[4][2] + red[4][3]);
        AST_F(&wf[WS_AMZ  + bc], fmaxf(fmaxf(red[5][0], red[5][1]), fmaxf(red[5][2], red[5][3])));
        AST_F(&wf[WS_AIN  + bc], fmaxf(fmaxf(red[6][0], red[6][1]), fmaxf(red[6][2], red[6][3])));
        if (c == 0) {
            __hip_atomic_store(&wi[WS_PLEN + b], plen, __ATOMIC_RELAXED, __HIP_MEMORY_SCOPE_AGENT);
            __hip_atomic_store(&wi[WS_MLEN + b], mlen, __ATOMIC_RELAXED, __HIP_MEMORY_SCOPE_AGENT);
        }
        // ACQ_REL: release publishes this block's partials; acquire (for the
        // winner) makes all 511 other blocks' partials visible.
        int old = __hip_atomic_fetch_add(cnt, 1, __ATOMIC_ACQ_REL, __HIP_MEMORY_SCOPE_AGENT);
        sflag = (old == NBLOCKS - 1);
    }
    __syncthreads();
    if (!sflag) return;

    // ================= last-arriving block: finalize =================
    __shared__ float terms[BATCH];
    __shared__ float red2[6][4];

    // soft-jaccard: batch bb's 16 partials at [16bb,16bb+16); thread t holds 2t,2t+1
    float sj = ALD_F(wf + WS_SJ + 2 * t) + ALD_F(wf + WS_SJ + 2 * t + 1);
    sj += __shfl_xor(sj, 1);
    sj += __shfl_xor(sj, 2);
    sj += __shfl_xor(sj, 4);
    if ((t & 7) == 0) {
        int bb = t >> 3;
        int pl = __hip_atomic_load(&wi[WS_PLEN + bb], __ATOMIC_RELAXED, __HIP_MEMORY_SCOPE_AGENT);
        int ml = __hip_atomic_load(&wi[WS_MLEN + bb], __ATOMIC_RELAXED, __HIP_MEMORY_SCOPE_AGENT);
        float su = (float)(pl + ml);
        terms[bb] = 1.0f - (sj + EPS) / (su + EPS);
    }

    float v1 = ALD_F(wf + WS_SSDM + 2 * t) + ALD_F(wf + WS_SSDM + 2 * t + 1);
    float v2 = ALD_F(wf + WS_SSDI + 2 * t) + ALD_F(wf + WS_SSDI + 2 * t + 1);
    float v3 = ALD_F(wf + WS_SGNM + 2 * t) + ALD_F(wf + WS_SGNM + 2 * t + 1);
    float v4 = ALD_F(wf + WS_SGNI + 2 * t) + ALD_F(wf + WS_SGNI + 2 * t + 1);
    float v5 = fmaxf(ALD_F(wf + WS_AMZ + 2 * t), ALD_F(wf + WS_AMZ + 2 * t + 1));
    float v6 = fmaxf(ALD_F(wf + WS_AIN + 2 * t), ALD_F(wf + WS_AIN + 2 * t + 1));
    v1 = waveSum(v1); v2 = waveSum(v2); v3 = waveSum(v3); v4 = waveSum(v4);
    v5 = waveMax(v5); v6 = waveMax(v6);
    if ((t & 63) == 0) {
        red2[0][wid] = v1; red2[1][wid] = v2; red2[2][wid] = v3;
        red2[3][wid] = v4; red2[4][wid] = v5; red2[5][wid] = v6;
    }
    __syncthreads();

    // wave 0: sum the 32 batch terms
    float term = (t < BATCH) ? terms[t] : 0.0f;
    if (t < 64) term = waveSum(term);

    if (t == 0) {
        float fssd_m = red2[0][0] + red2[0][1] + red2[0][2] + red2[0][3];
        float fssd_i = red2[1][0] + red2[1][1] + red2[1][2] + red2[1][3];
        float fsgn_m = red2[2][0] + red2[2][1] + red2[2][2] + red2[2][3];
        float fsgn_i = red2[3][0] + red2[3][1] + red2[3][2] + red2[3][3];
        float famz = fmaxf(fmaxf(red2[4][0], red2[4][1]), fmaxf(red2[4][2], red2[4][3]));
        float fain = fmaxf(fmaxf(red2[5][0], red2[5][1]), fmaxf(red2[5][2], red2[5][3]));
        out[0] = term / (float)BATCH;
        out[1] = (fssd_m / (float)NTOT) / (famz * famz);
        out[2] = (fssd_i / (float)NTOT) / (fain * fain);
        out[3] = 0.1f * 0.5f * (fsgn_m + fsgn_i) / (float)NTOT;
    }
}

extern "C" void kernel_launch(void* const* d_in, const int* in_sizes, int n_in,
                              void* d_out, int out_size, void* d_ws, size_t ws_size,
                              hipStream_t stream) {
    const float* pred_mz = (const float*)d_in[0];
    const float* mz      = (const float*)d_in[1];
    const float* inten   = (const float*)d_in[2];
    const float* pint    = (const float*)d_in[3];
    float* out = (float*)d_out;
    float* wf = (float*)d_ws;
    int*   wi = (int*)d_ws;
    int*   cnt = (int*)((char*)d_ws + (size_t)WS_CNT * 4);

    k_init<<<1, 1, 0, stream>>>(cnt);
    k_fused<<<dim3(BATCH, NCH), BLK, 0, stream>>>(pred_mz, mz, inten, pint,
                                                  wf, wi, cnt, out);
}

// Round 11
// 20.089 us; speedup vs baseline: 3.0736x; 1.3763x over previous
//
#include <hip/hip_runtime.h>

#define BATCH 32
#define SEQ 2048
#define NTOT (BATCH * SEQ)
#define EPS 1e-8f
#define BLK 256
#define SEGS 16
#define SEGLEN (SEQ / SEGS)       // 128 floats per segment
#define LDSW (SEGLEN + 4)         // +4-word pad -> 2-way bank aliasing only (free)
#define E 8                       // pred elements per thread (register-blocked)
#define GRP (BLK / SEGS)          // 16 pred groups per block
#define CBLK (GRP * E)            // 128 pred elements per block
#define NCH (SEQ / CBLK)          // 16 chunks per batch row
#define NPART (BATCH * NCH)       // 512 per-block partials
#define NBLOCKS (BATCH * NCH)
#define PADV 1e30f
#define MAGIC 0x5EED9E37

// ---- ws layout (4-byte words) ----
#define WS_SJ    0
#define WS_SSDM  (NPART)
#define WS_SSDI  (2 * NPART)
#define WS_SGNM  (3 * NPART)
#define WS_SGNI  (4 * NPART)
#define WS_AMZ   (5 * NPART)
#define WS_AIN   (6 * NPART)
#define WS_PLEN  (7 * NPART)       // int [32]
#define WS_MLEN  (7 * NPART + 32)  // int [32]
#define WS_FLAG  (7 * NPART + 64)  // int [512] per-block flags (self-resetting)

#define AST_F(p, v) __hip_atomic_store((p), (v), __ATOMIC_RELAXED, __HIP_MEMORY_SCOPE_AGENT)
#define ALD_F(p)    __hip_atomic_load((p), __ATOMIC_RELAXED, __HIP_MEMORY_SCOPE_AGENT)
#define AST_I(p, v) __hip_atomic_store((p), (v), __ATOMIC_RELAXED, __HIP_MEMORY_SCOPE_AGENT)
#define ALD_I(p)    __hip_atomic_load((p), __ATOMIC_RELAXED, __HIP_MEMORY_SCOPE_AGENT)
// release store / acquire load carry the fence semantics (no __hip_atomic_fence in this ROCm)
#define AST_REL(p, v) __hip_atomic_store((p), (v), __ATOMIC_RELEASE, __HIP_MEMORY_SCOPE_AGENT)
#define ALD_ACQ(p)    __hip_atomic_load((p), __ATOMIC_ACQUIRE, __HIP_MEMORY_SCOPE_AGENT)

__device__ inline float waveSum(float v) {
    #pragma unroll
    for (int off = 32; off; off >>= 1) v += __shfl_xor(v, off);
    return v;
}
__device__ inline float waveMax(float v) {
    #pragma unroll
    for (int off = 32; off; off >>= 1) v = fmaxf(v, __shfl_xor(v, off));
    return v;
}
__device__ inline int waveMaxI(int v) {
    #pragma unroll
    for (int off = 32; off; off >>= 1) v = max(v, __shfl_xor(v, off));
    return v;
}
__device__ inline float fsign(float x) {
    return (x > 0.0f) ? 1.0f : ((x < 0.0f) ? -1.0f : 0.0f);
}

// ==== single kernel: grid (BATCH, NCH) x BLK ====
// Phase 1: per-block partials (R4 structure). Each block release-stores its
// own flag = MAGIC (no RMW, no contention). Block (0,0) spins until all 512
// flags are MAGIC (acquire loads), finalizes, and resets flags to 0 so the
// next graph replay starts clean (no init node needed).
__global__ __launch_bounds__(BLK)
void k_fused(const float* __restrict__ pmz,  const float* __restrict__ mz,
             const float* __restrict__ inten, const float* __restrict__ pint,
             float* __restrict__ wf, int* __restrict__ wi,
             int* __restrict__ flags, float* __restrict__ out) {
    const int b = blockIdx.x;
    const int c = blockIdx.y;
    const int t = threadIdx.x;
    const int wid = t >> 6;

    __shared__ float mzs[SEGS * LDSW];
    __shared__ int   smP[4], smM[4];
    __shared__ float red[7][4];

    const float* mzrow = mz  + (size_t)b * SEQ;
    const float* prow  = pmz + (size_t)b * SEQ;

    // ---- stage mz row to LDS (segment-padded) + last-negative scans ----
    const int base  = t * 8;                        // word index in row
    const int lbase = base + ((base >> 7) << 2);    // +4 words per 128-word seg
    float4 mv0 = *(const float4*)(mzrow + base);
    float4 mv1 = *(const float4*)(mzrow + base + 4);
    float4 pv0 = *(const float4*)(prow  + base);
    float4 pv1 = *(const float4*)(prow  + base + 4);
    *(float4*)(mzs + lbase)     = mv0;
    *(float4*)(mzs + lbase + 4) = mv1;

    int lm = 0, lp = 0;   // ascending overwrite == index of last negative
    if (mv0.x < 0.f) lm = base + 0;  if (mv0.y < 0.f) lm = base + 1;
    if (mv0.z < 0.f) lm = base + 2;  if (mv0.w < 0.f) lm = base + 3;
    if (mv1.x < 0.f) lm = base + 4;  if (mv1.y < 0.f) lm = base + 5;
    if (mv1.z < 0.f) lm = base + 6;  if (mv1.w < 0.f) lm = base + 7;
    if (pv0.x < 0.f) lp = base + 0;  if (pv0.y < 0.f) lp = base + 1;
    if (pv0.z < 0.f) lp = base + 2;  if (pv0.w < 0.f) lp = base + 3;
    if (pv1.x < 0.f) lp = base + 4;  if (pv1.y < 0.f) lp = base + 5;
    if (pv1.z < 0.f) lp = base + 6;  if (pv1.w < 0.f) lp = base + 7;
    lm = waveMaxI(lm);  lp = waveMaxI(lp);
    if ((t & 63) == 0) { smM[wid] = lm; smP[wid] = lp; }
    __syncthreads();
    const int mlen = max(max(smM[0], smM[1]), max(smM[2], smM[3]));
    const int plen = max(max(smP[0], smP[1]), max(smP[2], smP[3]));

    // pad invalid tail: min -> ~1e30 -> exp -> 0 (also handles mlen==0)
    #pragma unroll
    for (int k = 0; k < 8; ++k)
        if (base + k >= mlen) mzs[lbase + k] = PADV;
    __syncthreads();

    // ---- stats on threads t < CBLK (one element each) ----
    float ssd_m = 0.f, ssd_i = 0.f, sgn_m = 0.f, sgn_i = 0.f, amz = 0.f, ain = 0.f;
    if (t < CBLK) {
        const int i = c * CBLK + t;
        const size_t idx = (size_t)b * SEQ + i;
        const float a  = prow[i];
        const float bm = mzrow[i];
        const float ci = pint[idx];
        const float di = inten[idx];
        float dm = a - bm;   ssd_m = dm * dm;
        float dd = ci - di;  ssd_i = dd * dd;
        sgn_m = fabsf(fsign(a)  - fsign(bm));
        sgn_i = fabsf(fsign(ci) - fsign(di));
        amz = fabsf(bm);
        ain = fabsf(di);
    }

    // ---- register-blocked min-scan ----
    const int s  = t & (SEGS - 1);       // segment id
    const int ig = t >> 4;               // pred group
    const int pb = c * CBLK + ig * E;    // first pred element of this thread
    float4 pa0 = *(const float4*)(prow + pb);
    float4 pa1 = *(const float4*)(prow + pb + 4);
    float a[E] = {pa0.x, pa0.y, pa0.z, pa0.w, pa1.x, pa1.y, pa1.z, pa1.w};
    float mn[E];
    #pragma unroll
    for (int e = 0; e < E; ++e) mn[e] = PADV;

    const float4* seg4 = (const float4*)(mzs + s * LDSW);
    #pragma unroll 4
    for (int j = 0; j < SEGLEN / 4; ++j) {
        float4 v = seg4[j];
        #pragma unroll
        for (int e = 0; e < E; ++e) {
            float d0 = a[e] - v.x, d1 = a[e] - v.y;
            float d2 = a[e] - v.z, d3 = a[e] - v.w;
            mn[e] = fminf(mn[e], fminf(fabsf(d0), fabsf(d1)));  // -> v_min3 |.|
            mn[e] = fminf(mn[e], fminf(fabsf(d2), fabsf(d3)));
        }
    }
    // combine the 16 segment minima (lanes ig*16 .. ig*16+15)
    #pragma unroll
    for (int e = 0; e < E; ++e) {
        float m = mn[e];
        m = fminf(m, __shfl_xor(m, 1));
        m = fminf(m, __shfl_xor(m, 2));
        m = fminf(m, __shfl_xor(m, 4));
        m = fminf(m, __shfl_xor(m, 8));
        mn[e] = m;
    }

    // contribution: s==0 lane of each group handles its 8 preds
    float contrib = 0.0f;
    if (s == 0) {
        const float* pintrow = pint + (size_t)b * SEQ;
        float4 w0 = *(const float4*)(pintrow + pb);
        float4 w1 = *(const float4*)(pintrow + pb + 4);
        float w[E] = {w0.x, w0.y, w0.z, w0.w, w1.x, w1.y, w1.z, w1.w};
        #pragma unroll
        for (int e = 0; e < E; ++e)
            if (pb + e < plen) contrib += __expf(-2.0f * mn[e]) * w[e];
    }

    // ---- block-reduce 7 partials ----
    float s0 = waveSum(contrib);
    float s1 = waveSum(ssd_m);
    float s2 = waveSum(ssd_i);
    float s3 = waveSum(sgn_m);
    float s4 = waveSum(sgn_i);
    float s5 = waveMax(amz);
    float s6 = waveMax(ain);
    if ((t & 63) == 0) {
        red[0][wid] = s0; red[1][wid] = s1; red[2][wid] = s2; red[3][wid] = s3;
        red[4][wid] = s4; red[5][wid] = s5; red[6][wid] = s6;
    }
    __syncthreads();
    if (t == 0) {
        const int bc = b * NCH + c;
        AST_F(&wf[WS_SJ   + bc], red[0][0] + red[0][1] + red[0][2] + red[0][3]);
        AST_F(&wf[WS_SSDM + bc], red[1][0] + red[1][1] + red[1][2] + red[1][3]);
        AST_F(&wf[WS_SSDI + bc], red[2][0] + red[2][1] + red[2][2] + red[2][3]);
        AST_F(&wf[WS_SGNM + bc], red[3][0] + red[3][1] + red[3][2] + red[3][3]);
        AST_F(&wf[WS_SGNI + bc], red[4][0] + red[4][1] + red[4][2] + red[4][3]);
        AST_F(&wf[WS_AMZ  + bc], fmaxf(fmaxf(red[5][0], red[5][1]), fmaxf(red[5][2], red[5][3])));
        AST_F(&wf[WS_AIN  + bc], fmaxf(fmaxf(red[6][0], red[6][1]), fmaxf(red[6][2], red[6][3])));
        if (c == 0) {
            AST_I(&wi[WS_PLEN + b], plen);
            AST_I(&wi[WS_MLEN + b], mlen);
        }
        // release store publishes this block's partial stores before the flag
        AST_REL(&flags[bc], MAGIC);
    }
    if (b != 0 || c != 0) return;

    // ================= block (0,0): wait for all flags, then finalize =================
    {
        const int f0 = t, f1 = t + BLK;   // 512 flags, 2 per thread
        while (ALD_ACQ(&flags[f0]) != MAGIC || ALD_ACQ(&flags[f1]) != MAGIC) {
            __builtin_amdgcn_s_sleep(2);
        }
    }
    __syncthreads();

    // reset flags for the next replay (no other writers at this point)
    AST_I(&flags[t], 0);
    AST_I(&flags[t + BLK], 0);

    __shared__ float terms[BATCH];
    __shared__ float red2[6][4];

    // soft-jaccard: batch bb's 16 partials at [16bb,16bb+16); thread t holds 2t,2t+1
    float sj = ALD_F(wf + WS_SJ + 2 * t) + ALD_F(wf + WS_SJ + 2 * t + 1);
    sj += __shfl_xor(sj, 1);
    sj += __shfl_xor(sj, 2);
    sj += __shfl_xor(sj, 4);
    if ((t & 7) == 0) {
        int bb = t >> 3;
        int pl = ALD_I(&wi[WS_PLEN + bb]);
        int ml = ALD_I(&wi[WS_MLEN + bb]);
        float su = (float)(pl + ml);
        terms[bb] = 1.0f - (sj + EPS) / (su + EPS);
    }

    float v1 = ALD_F(wf + WS_SSDM + 2 * t) + ALD_F(wf + WS_SSDM + 2 * t + 1);
    float v2 = ALD_F(wf + WS_SSDI + 2 * t) + ALD_F(wf + WS_SSDI + 2 * t + 1);
    float v3 = ALD_F(wf + WS_SGNM + 2 * t) + ALD_F(wf + WS_SGNM + 2 * t + 1);
    float v4 = ALD_F(wf + WS_SGNI + 2 * t) + ALD_F(wf + WS_SGNI + 2 * t + 1);
    float v5 = fmaxf(ALD_F(wf + WS_AMZ + 2 * t), ALD_F(wf + WS_AMZ + 2 * t + 1));
    float v6 = fmaxf(ALD_F(wf + WS_AIN + 2 * t), ALD_F(wf + WS_AIN + 2 * t + 1));
    v1 = waveSum(v1); v2 = waveSum(v2); v3 = waveSum(v3); v4 = waveSum(v4);
    v5 = waveMax(v5); v6 = waveMax(v6);
    if ((t & 63) == 0) {
        red2[0][wid] = v1; red2[1][wid] = v2; red2[2][wid] = v3;
        red2[3][wid] = v4; red2[4][wid] = v5; red2[5][wid] = v6;
    }
    __syncthreads();

    // wave 0: sum the 32 batch terms
    float term = (t < BATCH) ? terms[t] : 0.0f;
    if (t < 64) term = waveSum(term);

    if (t == 0) {
        float fssd_m = red2[0][0] + red2[0][1] + red2[0][2] + red2[0][3];
        float fssd_i = red2[1][0] + red2[1][1] + red2[1][2] + red2[1][3];
        float fsgn_m = red2[2][0] + red2[2][1] + red2[2][2] + red2[2][3];
        float fsgn_i = red2[3][0] + red2[3][1] + red2[3][2] + red2[3][3];
        float famz = fmaxf(fmaxf(red2[4][0], red2[4][1]), fmaxf(red2[4][2], red2[4][3]));
        float fain = fmaxf(fmaxf(red2[5][0], red2[5][1]), fmaxf(red2[5][2], red2[5][3]));
        out[0] = term / (float)BATCH;
        out[1] = (fssd_m / (float)NTOT) / (famz * famz);
        out[2] = (fssd_i / (float)NTOT) / (fain * fain);
        out[3] = 0.1f * 0.5f * (fsgn_m + fsgn_i) / (float)NTOT;
    }
}

extern "C" void kernel_launch(void* const* d_in, const int* in_sizes, int n_in,
                              void* d_out, int out_size, void* d_ws, size_t ws_size,
                              hipStream_t stream) {
    const float* pred_mz = (const float*)d_in[0];
    const float* mz      = (const float*)d_in[1];
    const float* inten   = (const float*)d_in[2];
    const float* pint    = (const float*)d_in[3];
    float* out = (float*)d_out;
    float* wf  = (float*)d_ws;
    int*   wi  = (int*)d_ws;
    int*   flags = (int*)d_ws + WS_FLAG;

    k_fused<<<dim3(BATCH, NCH), BLK, 0, stream>>>(pred_mz, mz, inten, pint,
                                                  wf, wi, flags, out);
}

// Round 12
// 15.854 us; speedup vs baseline: 3.8947x; 1.2672x over previous
//
#include <hip/hip_runtime.h>

#define BATCH 32
#define SEQ 2048
#define NTOT (BATCH * SEQ)
#define EPS 1e-8f
#define BLK 256
#define SEGS 16
#define SEGLEN (SEQ / SEGS)       // 128 floats per segment
#define LDSW (SEGLEN + 4)         // +4-word pad -> 2-way bank aliasing only (free)
#define E 8                       // pred elements per thread (register-blocked)
#define GRP (BLK / SEGS)          // 16 pred groups per block
#define CBLK (GRP * E)            // 128 pred elements per block
#define NCH (SEQ / CBLK)          // 16 chunks per batch row
#define NPART (BATCH * NCH)       // 512 sj partials
#define PADV 1e30f

// ---- ws layout (4-byte words) ---- plain overwrites only, no atomics/zeroing
#define WS_SJ    0                 // float [512]  per-block soft-intersect
#define WS_SSDM  512               // float [32]   per-row sum (pmz-mz)^2
#define WS_SSDI  544               // float [32]
#define WS_SGNM  576               // float [32]
#define WS_SGNI  608               // float [32]
#define WS_AMZ   640               // float [32]   per-row max |mz|
#define WS_AIN   672               // float [32]
#define WS_PLEN  704               // int   [32]
#define WS_MLEN  736               // int   [32]

__device__ inline float waveSum(float v) {
    #pragma unroll
    for (int off = 32; off; off >>= 1) v += __shfl_xor(v, off);
    return v;
}
__device__ inline float waveMax(float v) {
    #pragma unroll
    for (int off = 32; off; off >>= 1) v = fmaxf(v, __shfl_xor(v, off));
    return v;
}
__device__ inline int waveMaxI(int v) {
    #pragma unroll
    for (int off = 32; off; off >>= 1) v = max(v, __shfl_xor(v, off));
    return v;
}
__device__ inline float fsign(float x) {
    return (x > 0.0f) ? 1.0f : ((x < 0.0f) ? -1.0f : 0.0f);
}

// ==== main kernel: grid (BATCH, NCH) x BLK ====
// Staging thread t holds mz/pmz elements [8t, 8t+8) in registers; stats for the
// full row are computed HERE (from those registers) by the c==0 block only —
// no separate stats phase, no redundant per-chunk coverage.
__global__ __launch_bounds__(BLK)
void k_main(const float* __restrict__ pmz,  const float* __restrict__ mz,
            const float* __restrict__ inten, const float* __restrict__ pint,
            float* __restrict__ wf, int* __restrict__ wi) {
    const int b = blockIdx.x;
    const int c = blockIdx.y;
    const int t = threadIdx.x;
    const int wid = t >> 6;

    __shared__ float mzs[SEGS * LDSW];
    __shared__ int   smP[4], smM[4];
    __shared__ float red[7][4];

    const float* mzrow = mz  + (size_t)b * SEQ;
    const float* prow  = pmz + (size_t)b * SEQ;

    // ---- stage mz row to LDS (segment-padded) + last-negative scans ----
    const int base  = t * 8;                        // word index in row
    const int lbase = base + ((base >> 7) << 2);    // +4 words per 128-word seg
    float4 mv0 = *(const float4*)(mzrow + base);
    float4 mv1 = *(const float4*)(mzrow + base + 4);
    float4 pv0 = *(const float4*)(prow  + base);
    float4 pv1 = *(const float4*)(prow  + base + 4);
    *(float4*)(mzs + lbase)     = mv0;
    *(float4*)(mzs + lbase + 4) = mv1;

    int lm = 0, lp = 0;   // ascending overwrite == index of last negative
    if (mv0.x < 0.f) lm = base + 0;  if (mv0.y < 0.f) lm = base + 1;
    if (mv0.z < 0.f) lm = base + 2;  if (mv0.w < 0.f) lm = base + 3;
    if (mv1.x < 0.f) lm = base + 4;  if (mv1.y < 0.f) lm = base + 5;
    if (mv1.z < 0.f) lm = base + 6;  if (mv1.w < 0.f) lm = base + 7;
    if (pv0.x < 0.f) lp = base + 0;  if (pv0.y < 0.f) lp = base + 1;
    if (pv0.z < 0.f) lp = base + 2;  if (pv0.w < 0.f) lp = base + 3;
    if (pv1.x < 0.f) lp = base + 4;  if (pv1.y < 0.f) lp = base + 5;
    if (pv1.z < 0.f) lp = base + 6;  if (pv1.w < 0.f) lp = base + 7;

    // ---- full-row stats from staged registers (c==0 blocks only) ----
    float ssd_m = 0.f, ssd_i = 0.f, sgn_m = 0.f, sgn_i = 0.f, amz = 0.f, ain = 0.f;
    if (c == 0) {
        const float* irow = inten + (size_t)b * SEQ;
        const float* wrow = pint  + (size_t)b * SEQ;
        float4 iv0 = *(const float4*)(irow + base);
        float4 iv1 = *(const float4*)(irow + base + 4);
        float4 wv0 = *(const float4*)(wrow + base);
        float4 wv1 = *(const float4*)(wrow + base + 4);
        float pm[E] = {pv0.x, pv0.y, pv0.z, pv0.w, pv1.x, pv1.y, pv1.z, pv1.w};
        float mm[E] = {mv0.x, mv0.y, mv0.z, mv0.w, mv1.x, mv1.y, mv1.z, mv1.w};
        float ii[E] = {iv0.x, iv0.y, iv0.z, iv0.w, iv1.x, iv1.y, iv1.z, iv1.w};
        float ww[E] = {wv0.x, wv0.y, wv0.z, wv0.w, wv1.x, wv1.y, wv1.z, wv1.w};
        #pragma unroll
        for (int e = 0; e < E; ++e) {
            float dm = pm[e] - mm[e];  ssd_m += dm * dm;
            float dd = ww[e] - ii[e];  ssd_i += dd * dd;
            sgn_m += fabsf(fsign(pm[e]) - fsign(mm[e]));
            sgn_i += fabsf(fsign(ww[e]) - fsign(ii[e]));
            amz = fmaxf(amz, fabsf(mm[e]));
            ain = fmaxf(ain, fabsf(ii[e]));
        }
    }

    lm = waveMaxI(lm);  lp = waveMaxI(lp);
    if ((t & 63) == 0) { smM[wid] = lm; smP[wid] = lp; }
    __syncthreads();
    const int mlen = max(max(smM[0], smM[1]), max(smM[2], smM[3]));
    const int plen = max(max(smP[0], smP[1]), max(smP[2], smP[3]));

    // pad invalid tail: min -> ~1e30 -> exp -> 0 (also handles mlen==0)
    #pragma unroll
    for (int k = 0; k < 8; ++k)
        if (base + k >= mlen) mzs[lbase + k] = PADV;
    __syncthreads();

    // ---- register-blocked min-scan ----
    const int s  = t & (SEGS - 1);       // segment id
    const int ig = t >> 4;               // pred group
    const int pb = c * CBLK + ig * E;    // first pred element of this thread
    float4 pa0 = *(const float4*)(prow + pb);
    float4 pa1 = *(const float4*)(prow + pb + 4);
    float a[E] = {pa0.x, pa0.y, pa0.z, pa0.w, pa1.x, pa1.y, pa1.z, pa1.w};
    float mn[E];
    #pragma unroll
    for (int e = 0; e < E; ++e) mn[e] = PADV;

    const float4* seg4 = (const float4*)(mzs + s * LDSW);
    #pragma unroll 4
    for (int j = 0; j < SEGLEN / 4; ++j) {
        float4 v = seg4[j];
        #pragma unroll
        for (int e = 0; e < E; ++e) {
            float d0 = a[e] - v.x, d1 = a[e] - v.y;
            float d2 = a[e] - v.z, d3 = a[e] - v.w;
            mn[e] = fminf(mn[e], fminf(fabsf(d0), fabsf(d1)));  // -> v_min3 |.|
            mn[e] = fminf(mn[e], fminf(fabsf(d2), fabsf(d3)));
        }
    }
    // combine the 16 segment minima (lanes ig*16 .. ig*16+15)
    #pragma unroll
    for (int e = 0; e < E; ++e) {
        float m = mn[e];
        m = fminf(m, __shfl_xor(m, 1));
        m = fminf(m, __shfl_xor(m, 2));
        m = fminf(m, __shfl_xor(m, 4));
        m = fminf(m, __shfl_xor(m, 8));
        mn[e] = m;
    }

    // contribution: s==0 lane of each group handles its 8 preds
    float contrib = 0.0f;
    if (s == 0) {
        const float* pintrow = pint + (size_t)b * SEQ;
        float4 w0 = *(const float4*)(pintrow + pb);
        float4 w1 = *(const float4*)(pintrow + pb + 4);
        float w[E] = {w0.x, w0.y, w0.z, w0.w, w1.x, w1.y, w1.z, w1.w};
        #pragma unroll
        for (int e = 0; e < E; ++e)
            if (pb + e < plen) contrib += __expf(-2.0f * mn[e]) * w[e];
    }

    // ---- block-reduce 7 partials ----
    float s0 = waveSum(contrib);
    float s1 = waveSum(ssd_m);
    float s2 = waveSum(ssd_i);
    float s3 = waveSum(sgn_m);
    float s4 = waveSum(sgn_i);
    float s5 = waveMax(amz);
    float s6 = waveMax(ain);
    if ((t & 63) == 0) {
        red[0][wid] = s0; red[1][wid] = s1; red[2][wid] = s2; red[3][wid] = s3;
        red[4][wid] = s4; red[5][wid] = s5; red[6][wid] = s6;
    }
    __syncthreads();
    if (t == 0) {
        wf[WS_SJ + b * NCH + c] = red[0][0] + red[0][1] + red[0][2] + red[0][3];
        if (c == 0) {
            wf[WS_SSDM + b] = red[1][0] + red[1][1] + red[1][2] + red[1][3];
            wf[WS_SSDI + b] = red[2][0] + red[2][1] + red[2][2] + red[2][3];
            wf[WS_SGNM + b] = red[3][0] + red[3][1] + red[3][2] + red[3][3];
            wf[WS_SGNI + b] = red[4][0] + red[4][1] + red[4][2] + red[4][3];
            wf[WS_AMZ  + b] = fmaxf(fmaxf(red[5][0], red[5][1]), fmaxf(red[5][2], red[5][3]));
            wf[WS_AIN  + b] = fmaxf(fmaxf(red[6][0], red[6][1]), fmaxf(red[6][2], red[6][3]));
            wi[WS_PLEN + b] = plen;
            wi[WS_MLEN + b] = mlen;
        }
    }
}

// ==== finalize: 1 block x 256 threads ====
__global__ __launch_bounds__(BLK)
void k_final(const float* __restrict__ wf, const int* __restrict__ wi,
             float* __restrict__ out) {
    const int t = threadIdx.x;
    __shared__ float terms[BATCH];

    // soft-jaccard: batch bb's 16 partials at [16bb,16bb+16); thread t holds 2t,2t+1
    float2 v = *(const float2*)(wf + WS_SJ + 2 * t);
    float sj = v.x + v.y;
    sj += __shfl_xor(sj, 1);
    sj += __shfl_xor(sj, 2);
    sj += __shfl_xor(sj, 4);
    if ((t & 7) == 0) {
        int bb = t >> 3;
        float su = (float)(wi[WS_PLEN + bb] + wi[WS_MLEN + bb]);
        terms[bb] = 1.0f - (sj + EPS) / (su + EPS);
    }
    __syncthreads();

    // wave 0 handles everything else: 32 batch terms + 32-wide stat arrays
    if (t < 64) {
        float term = (t < BATCH) ? terms[t] : 0.0f;
        term = waveSum(term);
        float v1 = (t < BATCH) ? wf[WS_SSDM + t] : 0.0f;
        float v2 = (t < BATCH) ? wf[WS_SSDI + t] : 0.0f;
        float v3 = (t < BATCH) ? wf[WS_SGNM + t] : 0.0f;
        float v4 = (t < BATCH) ? wf[WS_SGNI + t] : 0.0f;
        float v5 = (t < BATCH) ? wf[WS_AMZ  + t] : 0.0f;
        float v6 = (t < BATCH) ? wf[WS_AIN  + t] : 0.0f;
        v1 = waveSum(v1); v2 = waveSum(v2); v3 = waveSum(v3); v4 = waveSum(v4);
        v5 = waveMax(v5); v6 = waveMax(v6);
        if (t == 0) {
            out[0] = term / (float)BATCH;
            out[1] = (v1 / (float)NTOT) / (v5 * v5);
            out[2] = (v2 / (float)NTOT) / (v6 * v6);
            out[3] = 0.1f * 0.5f * (v3 + v4) / (float)NTOT;
        }
    }
}

extern "C" void kernel_launch(void* const* d_in, const int* in_sizes, int n_in,
                              void* d_out, int out_size, void* d_ws, size_t ws_size,
                              hipStream_t stream) {
    const float* pred_mz = (const float*)d_in[0];
    const float* mz      = (const float*)d_in[1];
    const float* inten   = (const float*)d_in[2];
    const float* pint    = (const float*)d_in[3];
    float* out = (float*)d_out;
    float* wf = (float*)d_ws;
    int*   wi = (int*)d_ws;

    k_main<<<dim3(BATCH, NCH), BLK, 0, stream>>>(pred_mz, mz, inten, pint, wf, wi);
    k_final<<<1, BLK, 0, stream>>>(wf, wi, out);
}